// Round 8
// baseline (564.818 us; speedup 1.0000x reference)
//
#include <hip/hip_runtime.h>

// EncoderALSTM: T=128, B=32, H=256, I=256, 4H=1024.
// Round-8 = Round-7 (distributed scores, no h exchange, ZERO fences) plus:
//  (a) compute_gih: f16-packed W_ih + 16 (t,b) pairs/block (256 blocks) ->
//      weight re-stream 512 MB -> 128 MB, kernel ~40 -> ~8 us.
//  (b) score partials published BY THE CELL WAVE (64 lanes) right after the
//      cell, in-wave LDS handoff -> consumers' softmax starts ~1 barrier +
//      1 wave-handoff earlier. y/w publish stays post-barrier (lateness
//      hides under consumer softmax).
//  (c) softmax fused into the psx-poller wave (wave 7); ywp poll (tid<256)
//      runs concurrently.
//
// ws layout (bytes):
//   gih      @0         16,777,216  fp32 [t*32+b][1024]
//   Wih16    @16777216     524,288  u32 f16-pairs [k2][1024 r]
//   Whh_pack @17301504     524,288  uint4 [m][512 thr][8]
//   Wa_pack  @17825792     262,144  uint4 [m][256 j][8] (c<4 ctx, c>=4 h cols)
//   ywp      @18087936     524,288  u64 [32 b][8 m][256 j] tagged {y,w} partials
//   psx      @18612224     131,072  u64 [32 b][8 m][64]    tagged score pairs

#define T_DIM 128
#define B_DIM 32

typedef _Float16 half2_t __attribute__((ext_vector_type(2)));

static __device__ __forceinline__ unsigned pack2(float a, float b) {
  half2_t h;
  h.x = (_Float16)a;
  h.y = (_Float16)b;
  return __builtin_bit_cast(unsigned, h);
}

static __device__ __forceinline__ float dot2f(unsigned w, unsigned v, float acc) {
  half2_t a = __builtin_bit_cast(half2_t, w);
  half2_t b = __builtin_bit_cast(half2_t, v);
#if __has_builtin(__builtin_amdgcn_fdot2)
  return __builtin_amdgcn_fdot2(a, b, acc, false);
#else
  return acc + (float)a.x * (float)b.x + (float)a.y * (float)b.y;
#endif
}

static __device__ __forceinline__ float dot8(uint4 w, uint4 v, float acc) {
  acc = dot2f(w.x, v.x, acc);
  acc = dot2f(w.y, v.y, acc);
  acc = dot2f(w.z, v.z, acc);
  acc = dot2f(w.w, v.w, acc);
  return acc;
}

static __device__ __forceinline__ float lo16(unsigned u) {
  return (float)__builtin_bit_cast(half2_t, u).x;
}
static __device__ __forceinline__ float hi16(unsigned u) {
  return (float)__builtin_bit_cast(half2_t, u).y;
}

static __device__ __forceinline__ float fsig(float x) {
  return __builtin_amdgcn_rcpf(1.f + __expf(-x));
}
static __device__ __forceinline__ float ftanh(float x) {
  float e = __expf(2.f * x);
  return 1.f - 2.f * __builtin_amdgcn_rcpf(e + 1.f);
}

// ---------------- kernel 0: pack weights + zero tag buffers ----------------
__global__ void pack_weights(const float* __restrict__ W_ih, const float* __restrict__ W_hh,
                             const float* __restrict__ W_a, unsigned* __restrict__ Wih16,
                             uint4* __restrict__ Whh_pack, uint4* __restrict__ Wa_pack,
                             unsigned long long* __restrict__ ywp,
                             unsigned long long* __restrict__ psx) {
  int n = blockIdx.x * 256 + threadIdx.x;  // 0..262143
  if (n < 131072) {  // Wih16[k2][r] = f16x2 of W_ih[r][2k2..2k2+1]
    int k2 = n >> 10, r = n & 1023;
    const float* src = W_ih + r * 256 + 2 * k2;
    Wih16[n] = pack2(src[0], src[1]);
  }
  if (n < 32768) {  // Whh_pack[m][tid][i]: W_hh[r][(4i+qk)*8 ..+8]
    int m = n >> 12, tid = (n >> 3) & 511, i = n & 7;
    int r_local = tid >> 2, qk = tid & 3;
    int q = r_local >> 5, jl = r_local & 31;
    int r = q * 256 + m * 32 + jl;
    const float* src = W_hh + r * 256 + (4 * i + qk) * 8;
    uint4 v;
    v.x = pack2(src[0], src[1]);
    v.y = pack2(src[2], src[3]);
    v.z = pack2(src[4], src[5]);
    v.w = pack2(src[6], src[7]);
    Whh_pack[n] = v;
  }
  if (n < 16384) {  // Wa_pack[m][j][c]: c<4 ctx col m*32+c*8; c>=4 h col 256+m*32+(c-4)*8
    int m = n >> 11, j = (n >> 3) & 255, c = n & 7;
    int col0 = (c < 4) ? (m * 32 + c * 8) : (256 + m * 32 + (c - 4) * 8);
    const float* src = W_a + j * 512 + col0;
    uint4 v;
    v.x = pack2(src[0], src[1]);
    v.y = pack2(src[2], src[3]);
    v.z = pack2(src[4], src[5]);
    v.w = pack2(src[6], src[7]);
    Wa_pack[n] = v;
  }
  if (n < 65536)
    __hip_atomic_store(&ywp[n], 0ull, __ATOMIC_RELAXED, __HIP_MEMORY_SCOPE_AGENT);
  else if (n < 81920)
    __hip_atomic_store(&psx[n - 65536], 0ull, __ATOMIC_RELAXED, __HIP_MEMORY_SCOPE_AGENT);
}

// ---------------- kernel 1: gih = embs @ W_ih^T + b_ih + b_hh (f16 weights) ----------------
__global__ void compute_gih(const float* __restrict__ embs, const unsigned* __restrict__ Wih16,
                            const float* __restrict__ b_ih, const float* __restrict__ b_hh,
                            float* __restrict__ gih) {
  __shared__ unsigned embS16[16][128];
  const int tid = threadIdx.x;      // 256 threads
  const int tb0 = blockIdx.x * 16;  // 256 blocks x 16 (t,b) pairs
  for (int x = tid; x < 2048; x += 256) {
    int e = x >> 7, p = x & 127;
    const float* s = embs + (size_t)(tb0 + e) * 256 + 2 * p;
    embS16[e][p] = pack2(s[0], s[1]);
  }
  __syncthreads();
  float acc[16][4];
#pragma unroll
  for (int e = 0; e < 16; ++e)
#pragma unroll
    for (int q = 0; q < 4; ++q) acc[e][q] = 0.f;
  for (int k2 = 0; k2 < 128; ++k2) {
    unsigned w0 = Wih16[k2 * 1024 + tid];
    unsigned w1 = Wih16[k2 * 1024 + tid + 256];
    unsigned w2 = Wih16[k2 * 1024 + tid + 512];
    unsigned w3 = Wih16[k2 * 1024 + tid + 768];
#pragma unroll
    for (int e = 0; e < 16; ++e) {
      unsigned x = embS16[e][k2];
      acc[e][0] = dot2f(w0, x, acc[e][0]);
      acc[e][1] = dot2f(w1, x, acc[e][1]);
      acc[e][2] = dot2f(w2, x, acc[e][2]);
      acc[e][3] = dot2f(w3, x, acc[e][3]);
    }
  }
#pragma unroll
  for (int q = 0; q < 4; ++q) {
    float bias = b_ih[q * 256 + tid] + b_hh[q * 256 + tid];
#pragma unroll
    for (int e = 0; e < 16; ++e)
      gih[(size_t)(tb0 + e) * 1024 + q * 256 + tid] = acc[e][q] + bias;
  }
}

// ---------------- kernel 2: recurrent ----------------
__global__ void __launch_bounds__(512, 1)
alstm_rec(const int* __restrict__ lens, const float* __restrict__ gih,
          const uint4* __restrict__ Whh_pack, const uint4* __restrict__ Wa_pack,
          const float* __restrict__ b_a, unsigned long long* __restrict__ ywp,
          unsigned long long* __restrict__ psx, float* __restrict__ out,
          float* __restrict__ hfin, float* __restrict__ cfin) {
  const int tid = threadIdx.x;  // 512 threads
  const int b = blockIdx.x & 31;
  const int m = blockIdx.x >> 5;

  __shared__ __align__(16) unsigned histSl[128 * 20];  // own h slice history (stride 20), 10 KB
  __shared__ __align__(16) float ystoreF[128 * 256];   // y history f32, 128 KB
  __shared__ __align__(16) unsigned hp2[128];          // h' pairs
  __shared__ __align__(16) unsigned hsl2[16];          // own h_t slice pairs
  __shared__ float sc[128];                            // scores -> alpha
  __shared__ float zp[4][256];                         // z partials
  __shared__ float gsl[128];

  // ---- register-resident weights ----
  uint4 wh4[8];
  {
    const uint4* p = Whh_pack + ((size_t)m * 512 + tid) * 8;
#pragma unroll
    for (int i = 0; i < 8; ++i) wh4[i] = p[i];
  }
  uint4 way[4], waw[4];  // W_a slice cols for publish row j_pub = (tid-128)&255
  {
    const int j_pub = (tid - 128) & 255;
    const uint4* p = Wa_pack + ((size_t)m * 256 + j_pub) * 8;
#pragma unroll
    for (int i = 0; i < 4; ++i) way[i] = p[i];
#pragma unroll
    for (int i = 0; i < 4; ++i) waw[i] = p[4 + i];
  }
  const float ba_j = (tid < 256) ? b_a[tid] : 0.f;
  const int len_b = lens[b];
  const int r_local = tid >> 2, qk = tid & 3;
  const int gq = r_local >> 5, gjl = r_local & 31;

  if (tid < 128) hp2[tid] = 0u;
  float c_reg = 0.f;  // lanes tid<32
  __syncthreads();

  for (int t = 0; t < T_DIM; ++t) {
    float gih_v = gih[((size_t)t * 32 + b) * 1024 + gq * 256 + m * 32 + gjl];
    float w_j = 0.f;

    if (t > 0) {
      // ---- poll: ywp (tid<256) || psx + fused softmax (wave 7) ----
      if (tid < 256) {
        const unsigned long long* base = ywp + b * 2048 + tid;
        unsigned long long v[8];
        for (;;) {
          bool ok = true;
#pragma unroll
          for (int mm = 0; mm < 8; ++mm)
            v[mm] = __hip_atomic_load(base + mm * 256, __ATOMIC_RELAXED, __HIP_MEMORY_SCOPE_AGENT);
#pragma unroll
          for (int mm = 0; mm < 8; ++mm) ok &= ((unsigned)v[mm] == (unsigned)t);
          if (ok) break;
          __builtin_amdgcn_s_sleep(1);
        }
        float y = 0.f, w = 0.f;
#pragma unroll
        for (int mm = 0; mm < 8; ++mm) {
          unsigned pl = (unsigned)(v[mm] >> 32);
          y += lo16(pl);
          w += hi16(pl);
        }
        w_j = w;
        ystoreF[(t - 1) * 256 + tid] = y;
      } else if (tid >= 448) {
        const int lane = tid - 448;  // score pair index 0..63
        const unsigned long long* base = psx + b * 512 + lane;
        unsigned long long v[8];
        for (;;) {
          bool ok = true;
#pragma unroll
          for (int mm = 0; mm < 8; ++mm)
            v[mm] = __hip_atomic_load(base + mm * 64, __ATOMIC_RELAXED, __HIP_MEMORY_SCOPE_AGENT);
#pragma unroll
          for (int mm = 0; mm < 8; ++mm) ok &= ((unsigned)v[mm] == (unsigned)t);
          if (ok) break;
          __builtin_amdgcn_s_sleep(1);
        }
        float s0 = 0.f, s1 = 0.f;
#pragma unroll
        for (int mm = 0; mm < 8; ++mm) {
          unsigned pl = (unsigned)(v[mm] >> 32);
          s0 += lo16(pl);
          s1 += hi16(pl);
        }
        // fused softmax over 128 values (2 per lane), in-wave
        float v0 = (2 * lane < t) ? s0 : -3.0e38f;
        float v1 = (2 * lane + 1 < t) ? s1 : -3.0e38f;
        float mx = fmaxf(v0, v1);
#pragma unroll
        for (int off = 32; off >= 1; off >>= 1) mx = fmaxf(mx, __shfl_xor(mx, off));
        float e0 = (2 * lane < t) ? __expf(v0 - mx) : 0.f;
        float e1 = (2 * lane + 1 < t) ? __expf(v1 - mx) : 0.f;
        float sm = e0 + e1;
#pragma unroll
        for (int off = 32; off >= 1; off >>= 1) sm += __shfl_xor(sm, off);
        float inv = __builtin_amdgcn_rcpf(sm);
        sc[2 * lane] = e0 * inv;
        sc[2 * lane + 1] = e1 * inv;
      }
      __syncthreads();
      // ---- Z: z partials over f32 y-history ----
      {
        const int sp = tid >> 7, p2 = tid & 127;
        float c0 = 0.f, c1 = 0.f;
        const float* yb = ystoreF + 2 * p2;
        for (int s = sp; s < t; s += 4) {
          float al = sc[s];
          float2 yv = *(const float2*)(yb + s * 256);
          c0 += al * yv.x;
          c1 += al * yv.y;
        }
        zp[sp][2 * p2] = c0;
        zp[sp][2 * p2 + 1] = c1;
      }
      __syncthreads();
      // ---- H': h'_j = tanh(ba + w + z) ----
      if (tid < 256) {
        float z = zp[0][tid] + zp[1][tid] + zp[2][tid] + zp[3][tid];
        float hv = ftanh(ba_j + w_j + z);
        float o = __shfl_xor(hv, 1);
        if (!(tid & 1)) hp2[tid >> 1] = pack2(hv, o);
      }
      __syncthreads();
    }
    // ---- F: gates row r_local, chunks c==qk (mod 4) ----
    {
      float a = 0.f;
#pragma unroll
      for (int i = 0; i < 8; ++i) {
        const int c = 4 * i + qk;
        uint4 hv = *(const uint4*)&hp2[c << 2];
        a = dot8(wh4[i], hv, a);
      }
      a += __shfl_xor(a, 1);
      a += __shfl_xor(a, 2);
      if (qk == 0) gsl[r_local] = a + gih_v;
    }
    __syncthreads();
    // ---- cell + IMMEDIATE score-partial publish (wave 0, all 64 lanes) ----
    if (tid < 64) {
      if (tid < 32) {
        float ig = fsig(gsl[tid]);
        float fg = fsig(gsl[32 + tid]);
        float gg = ftanh(gsl[64 + tid]);
        float og = fsig(gsl[96 + tid]);
        float cn = fg * c_reg + ig * gg;
        float hn = og * ftanh(cn);
        c_reg = cn;
        out[((size_t)t * 32 + b) * 256 + m * 32 + tid] = hn;
        if (t == len_b - 1) {
          hfin[b * 256 + m * 32 + tid] = hn;
          cfin[b * 256 + m * 32 + tid] = cn;
        }
        float o = __shfl_xor(hn, 1);
        if (!(tid & 1)) {
          unsigned u = pack2(hn, o);
          hsl2[tid >> 1] = u;
          histSl[t * 20 + (tid >> 1)] = u;
        }
      }
      // in-wave handoff (lgkmcnt ordering, no barrier): all 64 lanes
      uint4 q0 = *(const uint4*)&hsl2[0];
      uint4 q1 = *(const uint4*)&hsl2[4];
      uint4 q2 = *(const uint4*)&hsl2[8];
      uint4 q3 = *(const uint4*)&hsl2[12];
      const int r0 = 2 * tid, r1 = 2 * tid + 1;
      float a0 = 0.f, a1 = 0.f;
      {
        uint4 h0, h1;
        h0 = *(const uint4*)&histSl[r0 * 20 + 0];
        h1 = *(const uint4*)&histSl[r1 * 20 + 0];
        a0 = dot8(h0, q0, a0);
        a1 = dot8(h1, q0, a1);
        h0 = *(const uint4*)&histSl[r0 * 20 + 4];
        h1 = *(const uint4*)&histSl[r1 * 20 + 4];
        a0 = dot8(h0, q1, a0);
        a1 = dot8(h1, q1, a1);
        h0 = *(const uint4*)&histSl[r0 * 20 + 8];
        h1 = *(const uint4*)&histSl[r1 * 20 + 8];
        a0 = dot8(h0, q2, a0);
        a1 = dot8(h1, q2, a1);
        h0 = *(const uint4*)&histSl[r0 * 20 + 12];
        h1 = *(const uint4*)&histSl[r1 * 20 + 12];
        a0 = dot8(h0, q3, a0);
        a1 = dot8(h1, q3, a1);
      }
      unsigned long long v = ((unsigned long long)pack2(a0, a1) << 32) |
                             (unsigned long long)(unsigned)(t + 1);
      __hip_atomic_store(&psx[b * 512 + m * 64 + tid], v, __ATOMIC_RELAXED,
                         __HIP_MEMORY_SCOPE_AGENT);
    }
    __syncthreads();
    // ---- y/w partial publish (tid 128..383) ----
    if (tid >= 128 && tid < 384) {
      const int j = tid - 128;
      float ay = 0.f, aw = 0.f;
#pragma unroll
      for (int c = 0; c < 4; ++c) {
        uint4 hv = *(const uint4*)&hsl2[c * 4];
        ay = dot8(way[c], hv, ay);
        aw = dot8(waw[c], hv, aw);
      }
      unsigned long long v = ((unsigned long long)pack2(ay, aw) << 32) |
                             (unsigned long long)(unsigned)(t + 1);
      __hip_atomic_store(&ywp[b * 2048 + m * 256 + j], v, __ATOMIC_RELAXED,
                         __HIP_MEMORY_SCOPE_AGENT);
    }
    // no barrier at loop wrap: next poll touches only global tags + disjoint LDS
  }
}

extern "C" void kernel_launch(void* const* d_in, const int* in_sizes, int n_in,
                              void* d_out, int out_size, void* d_ws, size_t ws_size,
                              hipStream_t stream) {
  const float* embs = (const float*)d_in[0];
  const int* lens = (const int*)d_in[1];
  const float* W_ih = (const float*)d_in[2];
  const float* W_hh = (const float*)d_in[3];
  const float* b_ih = (const float*)d_in[4];
  const float* b_hh = (const float*)d_in[5];
  const float* W_a = (const float*)d_in[6];
  const float* b_a = (const float*)d_in[7];

  float* out = (float*)d_out;                       // [T,B,H]
  float* hfin = out + (size_t)T_DIM * B_DIM * 256;  // [B,H]
  float* cfin = hfin + (size_t)B_DIM * 256;         // [B,H]

  char* ws = (char*)d_ws;
  float* gih = (float*)ws;
  unsigned* Wih16 = (unsigned*)(ws + 16777216);
  uint4* Whh_pack = (uint4*)(ws + 17301504);
  uint4* Wa_pack = (uint4*)(ws + 17825792);
  unsigned long long* ywp = (unsigned long long*)(ws + 18087936);
  unsigned long long* psx = (unsigned long long*)(ws + 18612224);

  pack_weights<<<1024, 256, 0, stream>>>(W_ih, W_hh, W_a, Wih16, Whh_pack, Wa_pack, ywp, psx);
  compute_gih<<<256, 256, 0, stream>>>(embs, Wih16, b_ih, b_hh, gih);
  alstm_rec<<<256, 512, 0, stream>>>(lens, gih, Whh_pack, Wa_pack, b_a, ywp, psx, out, hfin,
                                     cfin);
}